// Round 17
// baseline (231.820 us; speedup 1.0000x reference)
//
#include <hip/hip_runtime.h>
#include <cstdio>

typedef long long ll;
typedef unsigned long long ull;
typedef unsigned short ushort_t;
typedef __bf16 bf16x8 __attribute__((ext_vector_type(8)));
typedef float f32x4 __attribute__((ext_vector_type(4)));
typedef float f32x2 __attribute__((ext_vector_type(2)));

#define BB 4
#define NN 4096
#define CC 256
#define HH 512
#define GNUM 4
#define GS1 128
#define KNN 10

#define SC1 0.08838834764831845f   // 1/sqrt(128)
#define SC2 0.044194173824159216f  // 1/sqrt(512)

// WT segment offsets (elements)
#define OFF_FC1T   0
#define OFF_WD2T   131072
#define OFF_FGH1T  147456
#define OFF_FGH2T  163840
#define OFF_WDT    180224
#define OFF_FG1T   442368
#define OFF_FG2T   704512
#define OFF_WVST   966656
#define OFF_FD2T   1228800
#define OFF_FC2T   1490944
#define WT_TOTAL   1622016

__device__ inline unsigned pk2(float x, float y) {
  unsigned a = __float_as_uint(x), b = __float_as_uint(y);
  a = (a + 0x7FFFu + ((a >> 16) & 1u)) >> 16;
  b = (b + 0x7FFFu + ((b >> 16) & 1u)) >> 16;
  return a | (b << 16);
}
__device__ inline ushort_t bf1(float x) {
  unsigned a = __float_as_uint(x);
  return (ushort_t)((a + 0x7FFFu + ((a >> 16) & 1u)) >> 16);
}
__device__ inline float b2f(ushort_t u) { return __uint_as_float((unsigned)u << 16); }
__device__ inline int sw16(int r) { return ((r ^ (r >> 3)) & 7) << 4; }

// chunked bijective XCD swizzle (nwg must be divisible by 8)
__device__ inline void xcd_map(int& bx, int& by, int& bz) {
  const int nx = gridDim.x, ny = gridDim.y;
  const int nwg = nx * ny * gridDim.z;
  const int bidf = blockIdx.x + nx * (blockIdx.y + ny * blockIdx.z);
  const int lid = (bidf & 7) * (nwg >> 3) + (bidf >> 3);
  bx = lid % nx;
  const int rem = lid / nx;
  by = rem % ny;
  bz = rem / ny;
}

// ---------------- weight convert: WT[n][k] bf16 = (src - src2)[k][n] ----------------
__global__ __launch_bounds__(256) void wconv_k(
    const float* __restrict__ fc1w, const float* __restrict__ wqs2, const float* __restrict__ wks2,
    const float* __restrict__ fgh1, const float* __restrict__ fgh2,
    const float* __restrict__ wqs, const float* __restrict__ wks,
    const float* __restrict__ fg1, const float* __restrict__ fg2,
    const float* __restrict__ wvs, const float* __restrict__ fd2,
    const float* __restrict__ fc2w, ushort_t* __restrict__ WT)
{
  const int gc = blockIdx.x * 256 + threadIdx.x;
  const int e0 = gc * 8;
  if (e0 >= WT_TOTAL) return;
  const float* src = nullptr; const float* src2 = nullptr;
  int off, Kd, Nd;
  if (e0 < OFF_WD2T)        { src = fc1w;             off = OFF_FC1T;  Kd = 256; Nd = 512; }
  else if (e0 < OFF_FGH1T)  { src = wqs2; src2 = wks2; off = OFF_WD2T;  Kd = 128; Nd = 128; }
  else if (e0 < OFF_FGH2T)  { src = fgh1;             off = OFF_FGH1T; Kd = 128; Nd = 128; }
  else if (e0 < OFF_WDT)    { src = fgh2;             off = OFF_FGH2T; Kd = 128; Nd = 128; }
  else if (e0 < OFF_FG1T)   { src = wqs;  src2 = wks;  off = OFF_WDT;   Kd = 512; Nd = 512; }
  else if (e0 < OFF_FG2T)   { src = fg1;              off = OFF_FG1T;  Kd = 512; Nd = 512; }
  else if (e0 < OFF_WVST)   { src = fg2;              off = OFF_FG2T;  Kd = 512; Nd = 512; }
  else if (e0 < OFF_FD2T)   { src = wvs;              off = OFF_WVST;  Kd = 512; Nd = 512; }
  else if (e0 < OFF_FC2T)   { src = fd2;              off = OFF_FD2T;  Kd = 512; Nd = 512; }
  else                      { src = fc2w;             off = OFF_FC2T;  Kd = 512; Nd = 256; }
  const int local = e0 - off;
  const int n = local / Kd, k0 = local % Kd;
  ushort_t outv[8];
  #pragma unroll
  for (int j = 0; j < 8; ++j) {
    float v = src[(ll)(k0 + j) * Nd + n];
    if (src2) v -= src2[(ll)(k0 + j) * Nd + n];
    outv[j] = bf1(v);
  }
  *reinterpret_cast<uint4*>(WT + e0) = *reinterpret_cast<uint4*>(outv);
}

// ---------------- bf16 MFMA GEMM (B pre-transposed bf16 [n][k]) ----------------
// ATRANS: A f32 stored [k][m] with row stride lda. else A bf16 row-major [m][k].
// EPI: 0 store bf16, 1 +bias bf16, 2 +bias relu bf16, 4 +bias f32 transposed store + pre
template<bool ATRANS, int EPI>
__global__ __launch_bounds__(256, 2) void mgemm_k(
    const void* __restrict__ Ain, const ushort_t* __restrict__ BT,
    const float* __restrict__ bias, void* __restrict__ CoutV,
    const float* __restrict__ pre,
    int M, int N, int K, int lda, ll strideA, ll strideC)
{
  int bx, by, z;
  xcd_map(bx, by, z);
  const int bm = by * 128;
  const int bn = bx * 128;
  __shared__ alignas(16) char smem[32768];
  char* smA = smem;
  char* smB = smem + 16384;
  const int tid = threadIdx.x;
  const int lane = tid & 63, w = tid >> 6;
  const int lr = lane & 15, lg = lane >> 4;
  const int wm = (w & 1) * 64, wn = (w >> 1) * 64;

  const ushort_t* Ab = ATRANS ? nullptr : ((const ushort_t*)Ain + (ll)z * strideA);
  const float*    Af = ATRANS ? ((const float*)Ain + (ll)z * strideA) : nullptr;

  f32x4 acc[4][4] = {};

  for (int k0 = 0; k0 < K; k0 += 64) {
    if (!ATRANS) {
      #pragma unroll
      for (int p = 0; p < 4; ++p) {
        const int i = p * 256 + tid;
        const int r = i >> 3, c8 = (i & 7) * 8;
        const uint4 v = *reinterpret_cast<const uint4*>(Ab + (ll)(bm + r) * lda + (k0 + c8));
        *reinterpret_cast<uint4*>(smA + r * 128 + ((c8 * 2) ^ sw16(r))) = v;
      }
    } else {
      #pragma unroll
      for (int p = 0; p < 2; ++p) {
        const int bb = p * 256 + tid;
        const int mb = (bb & 31) * 4, kb = (bb >> 5) * 4;
        const float4 l0 = *reinterpret_cast<const float4*>(Af + (ll)(k0 + kb + 0) * lda + (bm + mb));
        const float4 l1 = *reinterpret_cast<const float4*>(Af + (ll)(k0 + kb + 1) * lda + (bm + mb));
        const float4 l2 = *reinterpret_cast<const float4*>(Af + (ll)(k0 + kb + 2) * lda + (bm + mb));
        const float4 l3 = *reinterpret_cast<const float4*>(Af + (ll)(k0 + kb + 3) * lda + (bm + mb));
        *reinterpret_cast<uint2*>(smA + (mb + 0) * 128 + ((kb * 2) ^ sw16(mb + 0))) = make_uint2(pk2(l0.x, l1.x), pk2(l2.x, l3.x));
        *reinterpret_cast<uint2*>(smA + (mb + 1) * 128 + ((kb * 2) ^ sw16(mb + 1))) = make_uint2(pk2(l0.y, l1.y), pk2(l2.y, l3.y));
        *reinterpret_cast<uint2*>(smA + (mb + 2) * 128 + ((kb * 2) ^ sw16(mb + 2))) = make_uint2(pk2(l0.z, l1.z), pk2(l2.z, l3.z));
        *reinterpret_cast<uint2*>(smA + (mb + 3) * 128 + ((kb * 2) ^ sw16(mb + 3))) = make_uint2(pk2(l0.w, l1.w), pk2(l2.w, l3.w));
      }
    }
    // B tile: rows n, cols k (pre-transposed bf16, row stride K)
    #pragma unroll
    for (int p = 0; p < 4; ++p) {
      const int i = p * 256 + tid;
      const int r = i >> 3, c8 = (i & 7) * 8;
      const uint4 v = *reinterpret_cast<const uint4*>(BT + (ll)(bn + r) * K + (k0 + c8));
      *reinterpret_cast<uint4*>(smB + r * 128 + ((c8 * 2) ^ sw16(r))) = v;
    }
    __syncthreads();

    #pragma unroll
    for (int ks = 0; ks < 2; ++ks) {
      bf16x8 af[4], bfr[4];
      #pragma unroll
      for (int mi = 0; mi < 4; ++mi) {
        const int r = wm + mi * 16 + lr;
        af[mi] = *reinterpret_cast<const bf16x8*>(smA + r * 128 + ((((ks << 2) + lg) << 4) ^ sw16(r)));
      }
      #pragma unroll
      for (int ni = 0; ni < 4; ++ni) {
        const int r = wn + ni * 16 + lr;
        bfr[ni] = *reinterpret_cast<const bf16x8*>(smB + r * 128 + ((((ks << 2) + lg) << 4) ^ sw16(r)));
      }
      #pragma unroll
      for (int mi = 0; mi < 4; ++mi)
        #pragma unroll
        for (int ni = 0; ni < 4; ++ni)
          acc[mi][ni] = __builtin_amdgcn_mfma_f32_16x16x32_bf16(af[mi], bfr[ni], acc[mi][ni], 0, 0, 0);
    }
    __syncthreads();
  }

  #pragma unroll
  for (int ni = 0; ni < 4; ++ni) {
    const int col = bn + wn + ni * 16 + lr;
    const float bv = (EPI != 0) ? bias[col] : 0.f;
    #pragma unroll
    for (int mi = 0; mi < 4; ++mi) {
      const int row0 = bm + wm + mi * 16 + lg * 4;
      if (EPI == 4) {
        float* Cout = (float*)CoutV;
        const size_t o = ((size_t)z * N + col) * (size_t)M + row0;
        const float4 pv = *reinterpret_cast<const float4*>(pre + o);
        float4 r;
        r.x = acc[mi][ni][0] + bv + pv.x;
        r.y = acc[mi][ni][1] + bv + pv.y;
        r.z = acc[mi][ni][2] + bv + pv.z;
        r.w = acc[mi][ni][3] + bv + pv.w;
        *reinterpret_cast<float4*>(Cout + o) = r;
      } else {
        ushort_t* Co = (ushort_t*)CoutV + (ll)z * strideC;
        #pragma unroll
        for (int i = 0; i < 4; ++i) {
          float val = acc[mi][ni][i] + bv;
          if (EPI == 2) val = fmaxf(val, 0.f);
          Co[(ll)(row0 + i) * N + col] = bf1(val);
        }
      }
    }
  }
}

// ---------------- fused V+res kernel: R = softmaxmix(P,A2) * (X@wvT + HM@fd2T + bias) ----------------
// Epilogue stages V into a padded LDS tile, then does a fully coalesced res pass.
__global__ __launch_bounds__(256, 2) void gemm_vpe_res_k(
    const ushort_t* __restrict__ X, const ushort_t* __restrict__ HM,
    const ushort_t* __restrict__ wvT, const ushort_t* __restrict__ w2T,
    const float* __restrict__ bias,
    const ushort_t* __restrict__ P, const ushort_t* __restrict__ A2,
    const float* __restrict__ M1, const float* __restrict__ R1,
    const float* __restrict__ M2, const float* __restrict__ R2,
    ushort_t* __restrict__ Rout)
{
  int bx, by, z;
  xcd_map(bx, by, z);
  const int bm = by * 128;
  const int bn = bx * 128;
  __shared__ alignas(16) char smem[34816];   // K-loop: smA(16K)+smB(16K); epilogue: Vt[128][136] bf16
  char* smA = smem;
  char* smB = smem + 16384;
  const int tid = threadIdx.x;
  const int lane = tid & 63, w = tid >> 6;
  const int lr = lane & 15, lg = lane >> 4;
  const int wm = (w & 1) * 64, wn = (w >> 1) * 64;

  f32x4 acc[4][4] = {};

  for (int k0 = 0; k0 < 1024; k0 += 64) {
    const ushort_t* A = (k0 < 512) ? X : HM;
    const ushort_t* BT = (k0 < 512) ? wvT : w2T;
    const int kk = k0 & 511;
    #pragma unroll
    for (int p = 0; p < 4; ++p) {
      const int i = p * 256 + tid;
      const int r = i >> 3, c8 = (i & 7) * 8;
      const uint4 v = *reinterpret_cast<const uint4*>(A + (ll)(bm + r) * 512 + (kk + c8));
      *reinterpret_cast<uint4*>(smA + r * 128 + ((c8 * 2) ^ sw16(r))) = v;
    }
    #pragma unroll
    for (int p = 0; p < 4; ++p) {
      const int i = p * 256 + tid;
      const int r = i >> 3, c8 = (i & 7) * 8;
      const uint4 v = *reinterpret_cast<const uint4*>(BT + (ll)(bn + r) * 512 + (kk + c8));
      *reinterpret_cast<uint4*>(smB + r * 128 + ((c8 * 2) ^ sw16(r))) = v;
    }
    __syncthreads();

    #pragma unroll
    for (int ks = 0; ks < 2; ++ks) {
      bf16x8 af[4], bfr[4];
      #pragma unroll
      for (int mi = 0; mi < 4; ++mi) {
        const int r = wm + mi * 16 + lr;
        af[mi] = *reinterpret_cast<const bf16x8*>(smA + r * 128 + ((((ks << 2) + lg) << 4) ^ sw16(r)));
      }
      #pragma unroll
      for (int ni = 0; ni < 4; ++ni) {
        const int r = wn + ni * 16 + lr;
        bfr[ni] = *reinterpret_cast<const bf16x8*>(smB + r * 128 + ((((ks << 2) + lg) << 4) ^ sw16(r)));
      }
      #pragma unroll
      for (int mi = 0; mi < 4; ++mi)
        #pragma unroll
        for (int ni = 0; ni < 4; ++ni)
          acc[mi][ni] = __builtin_amdgcn_mfma_f32_16x16x32_bf16(af[mi], bfr[ni], acc[mi][ni], 0, 0, 0);
    }
    __syncthreads();
  }

  // stage V (+bias) into padded LDS tile (last __syncthreads already passed)
  ushort_t (*Vt)[136] = reinterpret_cast<ushort_t (*)[136]>(smem);
  #pragma unroll
  for (int ni = 0; ni < 4; ++ni) {
    const int col = wn + ni * 16 + lr;
    const float bv = bias[bn + col];
    #pragma unroll
    for (int mi = 0; mi < 4; ++mi) {
      const int row0 = wm + mi * 16 + lg * 4;
      #pragma unroll
      for (int i = 0; i < 4; ++i)
        Vt[row0 + i][col] = bf1(acc[mi][ni][i] + bv);
    }
  }
  __syncthreads();

  // coalesced res pass: 8 contiguous cols per thread-chunk
  const int bb = bm >> 12;          // batch index (block rows never straddle a batch)
  for (int it = 0; it < 8; ++it) {
    const int chunk = it * 256 + tid;
    const int lrow = chunk >> 4;
    const int c8 = (chunk & 15) * 8;
    const int grow = bm + lrow;
    const int gcol = bn + c8;
    const int rb = grow & 1023;
    const uint4 pu = *reinterpret_cast<const uint4*>(P + (ll)grow * 512 + gcol);
    const uint4 au = *reinterpret_cast<const uint4*>(A2 + ((ll)bb * 1024 + rb) * 512 + gcol);
    const uint4 vu = *reinterpret_cast<const uint4*>(&Vt[lrow][c8]);
    const int c = bb * 512 + gcol;
    float m1v[8], r1v[8], m2v[8], r2v[8];
    *reinterpret_cast<float4*>(m1v)     = *reinterpret_cast<const float4*>(M1 + c);
    *reinterpret_cast<float4*>(m1v + 4) = *reinterpret_cast<const float4*>(M1 + c + 4);
    *reinterpret_cast<float4*>(r1v)     = *reinterpret_cast<const float4*>(R1 + c);
    *reinterpret_cast<float4*>(r1v + 4) = *reinterpret_cast<const float4*>(R1 + c + 4);
    *reinterpret_cast<float4*>(m2v)     = *reinterpret_cast<const float4*>(M2 + c);
    *reinterpret_cast<float4*>(m2v + 4) = *reinterpret_cast<const float4*>(M2 + c + 4);
    *reinterpret_cast<float4*>(r2v)     = *reinterpret_cast<const float4*>(R2 + c);
    *reinterpret_cast<float4*>(r2v + 4) = *reinterpret_cast<const float4*>(R2 + c + 4);
    const unsigned* pw = reinterpret_cast<const unsigned*>(&pu);
    const unsigned* aw = reinterpret_cast<const unsigned*>(&au);
    const unsigned* vw = reinterpret_cast<const unsigned*>(&vu);
    float r[8];
    #pragma unroll
    for (int e = 0; e < 8; ++e) {
      const unsigned wsel = (e >> 1);
      const ushort_t pv = (ushort_t)((pw[wsel] >> ((e & 1) * 16)) & 0xFFFF);
      const ushort_t av = (ushort_t)((aw[wsel] >> ((e & 1) * 16)) & 0xFFFF);
      const ushort_t vv = (ushort_t)((vw[wsel] >> ((e & 1) * 16)) & 0xFFFF);
      r[e] = (expf((b2f(pv) - m1v[e]) * SC1) * r1v[e] + expf((b2f(av) - m2v[e]) * SC2) * r2v[e]) * b2f(vv);
    }
    uint4 ru;
    ru.x = pk2(r[0], r[1]);
    ru.y = pk2(r[2], r[3]);
    ru.z = pk2(r[4], r[5]);
    ru.w = pk2(r[6], r[7]);
    *reinterpret_cast<uint4*>(Rout + (ll)grow * 512 + gcol) = ru;
  }
}

// ---------------- fused branch-1 chain ----------------
__device__ __forceinline__ void gemm128(const char* smA, const char* smW, int wrow, int lr, int lg,
                                        f32x4 acc[8]) {
  #pragma unroll
  for (int ks = 0; ks < 4; ++ks) {
    const int koff = (ks * 4 + lg) * 16;
    const int ra = wrow + lr;
    const bf16x8 a = *reinterpret_cast<const bf16x8*>(smA + ra * 256 + (koff ^ sw16(ra)));
    #pragma unroll
    for (int ni = 0; ni < 8; ++ni) {
      const int rn = ni * 16 + lr;
      const bf16x8 b = *reinterpret_cast<const bf16x8*>(smW + rn * 256 + (koff ^ sw16(rn)));
      acc[ni] = __builtin_amdgcn_mfma_f32_16x16x32_bf16(a, b, acc[ni], 0, 0, 0);
    }
  }
}

// stage 128x128 bf16 weight (pre-transposed [n][k]) into swizzled LDS
__device__ __forceinline__ void stageWTb(const ushort_t* __restrict__ W, char* smW, int tid) {
  #pragma unroll
  for (int p = 0; p < 4; ++p) {
    const int i = p * 512 + tid;
    const int r = i >> 4, c8 = (i & 15) * 8;
    const uint4 v = *reinterpret_cast<const uint4*>(W + r * 128 + c8);
    *reinterpret_cast<uint4*>(smW + r * 256 + ((c8 * 2) ^ sw16(r))) = v;
  }
}

__global__ __launch_bounds__(512, 4) void fused1_k(
    const ushort_t* __restrict__ X,
    const ushort_t* __restrict__ wd2T,
    const ushort_t* __restrict__ w2T, const float* __restrict__ b2g,
    const ushort_t* __restrict__ w3T, const float* __restrict__ b3g,
    ushort_t* __restrict__ P)
{
  __shared__ alignas(16) char smT[32768];
  __shared__ alignas(16) char smW[32768];
  const int tid = threadIdx.x;
  const int lane = tid & 63, w = tid >> 6;
  const int lr = lane & 15, lg = lane >> 4;
  const int wrow = w * 16;
  const ll blockRow = (ll)blockIdx.x * 128;
  const ushort_t* Xb = X + blockRow * 128;

  float b2r[8], b3r[8];
  #pragma unroll
  for (int ni = 0; ni < 8; ++ni) { b2r[ni] = b2g[ni * 16 + lr]; b3r[ni] = b3g[ni * 16 + lr]; }

  #pragma unroll
  for (int p = 0; p < 4; ++p) {
    const int i = p * 512 + tid;
    const int r = i >> 4, c8 = (i & 15) * 8;
    const uint4 v = *reinterpret_cast<const uint4*>(Xb + (ll)r * 128 + c8);
    *reinterpret_cast<uint4*>(smT + r * 256 + ((c8 * 2) ^ sw16(r))) = v;
  }
  stageWTb(wd2T, smW, tid);
  __syncthreads();

  f32x4 acc[8];
  #pragma unroll
  for (int ni = 0; ni < 8; ++ni) acc[ni] = f32x4{0.f, 0.f, 0.f, 0.f};
  gemm128(smT, smW, wrow, lr, lg, acc);        // T1 = X @ WD2
  __syncthreads();

  #pragma unroll
  for (int ni = 0; ni < 8; ++ni)
    #pragma unroll
    for (int i = 0; i < 4; ++i) {
      const int r = wrow + lg * 4 + i;
      *reinterpret_cast<ushort_t*>(smT + r * 256 + (((ni * 16 + lr) * 2) ^ sw16(r))) = bf1(acc[ni][i]);
    }
  stageWTb(w2T, smW, tid);
  __syncthreads();

  #pragma unroll
  for (int ni = 0; ni < 8; ++ni) acc[ni] = f32x4{0.f, 0.f, 0.f, 0.f};
  gemm128(smT, smW, wrow, lr, lg, acc);        // U = T1 @ fgh1
  __syncthreads();

  #pragma unroll
  for (int ni = 0; ni < 8; ++ni)
    #pragma unroll
    for (int i = 0; i < 4; ++i) {
      const int r = wrow + lg * 4 + i;
      *reinterpret_cast<ushort_t*>(smT + r * 256 + (((ni * 16 + lr) * 2) ^ sw16(r))) =
          bf1(fmaxf(acc[ni][i] + b2r[ni], 0.f));
    }
  stageWTb(w3T, smW, tid);
  __syncthreads();

  #pragma unroll
  for (int ni = 0; ni < 8; ++ni) acc[ni] = f32x4{0.f, 0.f, 0.f, 0.f};
  gemm128(smT, smW, wrow, lr, lg, acc);        // P = U @ fgh2

  #pragma unroll
  for (int ni = 0; ni < 8; ++ni)
    #pragma unroll
    for (int i = 0; i < 4; ++i) {
      const ll r = blockRow + wrow + lg * 4 + i;
      P[r * 128 + ni * 16 + lr] = bf1(acc[ni][i] + b3r[ni]);
    }
}

// ---------------- online softmax partial reduce (bf16 inputs), merged ----------------
__device__ inline void omax_upd(float& m, float& s, float v, float scale) {
  if (v > m) { s = s * expf((m - v) * scale) + 1.0f; m = v; }
  else       { s += expf((v - m) * scale); }
}
__device__ inline void omax_merge(float& m, float& s, float m2, float s2, float scale) {
  if (m2 > m) { s = s * expf((m - m2) * scale) + s2; m = m2; }
  else        { s += s2 * expf((m2 - m) * scale); }
}

// grid 640: blocks [0,512) = branch-1 reduce, [512,640) = branch-2 reduce
__global__ __launch_bounds__(256) void red12_k(const ushort_t* __restrict__ P, const ushort_t* __restrict__ A2,
                                               float* __restrict__ PM1, float* __restrict__ PS1,
                                               float* __restrict__ PM2, float* __restrict__ PS2) {
  __shared__ float sm[256], ss[256];
  if (blockIdx.x < 512) {
    const int bid = blockIdx.x;
    const int b = bid >> 7, g = (bid >> 5) & 3, seg = bid & 31;
    const int d = threadIdx.x & 127, half = threadIdx.x >> 7;
    const size_t base = (size_t)b * NN * HH + g * GS1 + d;
    float m = -3.4e38f, s = 0.f;
    const int n0 = seg * 128 + half * 64;
    for (int n = n0; n < n0 + 64; ++n)
      omax_upd(m, s, b2f(P[base + (size_t)n * HH]), SC1);
    sm[threadIdx.x] = m; ss[threadIdx.x] = s;
    __syncthreads();
    if (half == 0) {
      omax_merge(m, s, sm[threadIdx.x + 128], ss[threadIdx.x + 128], SC1);
      const int c = b * HH + g * GS1 + d;
      PM1[(size_t)seg * 2048 + c] = m;
      PS1[(size_t)seg * 2048 + c] = s;
    }
  } else {
    const int bid = blockIdx.x - 512;
    const int b = bid >> 5, hb = (bid >> 3) & 3, seg = bid & 7;
    const int hl = threadIdx.x & 127, half = threadIdx.x >> 7;
    const int h = hb * 128 + hl;
    const size_t base = (size_t)b * 1024 * HH + h;
    float m = -3.4e38f, s = 0.f;
    const int r0 = seg * 128 + half * 64;
    for (int r = r0; r < r0 + 64; ++r)
      omax_upd(m, s, b2f(A2[base + (size_t)r * HH]), SC2);
    sm[threadIdx.x] = m; ss[threadIdx.x] = s;
    __syncthreads();
    if (half == 0) {
      omax_merge(m, s, sm[threadIdx.x + 128], ss[threadIdx.x + 128], SC2);
      const int c = b * HH + h;
      PM2[(size_t)seg * 2048 + c] = m;
      PS2[(size_t)seg * 2048 + c] = s;
    }
  }
}

// grid 16: blocks [0,8) combine branch-1 (nseg 32, SC1), [8,16) combine branch-2 (nseg 8, SC2)
__global__ __launch_bounds__(256) void combine12_k(const float* __restrict__ PM1, const float* __restrict__ PS1,
                                                   const float* __restrict__ PM2, const float* __restrict__ PS2,
                                                   float* __restrict__ M1, float* __restrict__ R1,
                                                   float* __restrict__ M2, float* __restrict__ R2) {
  if (blockIdx.x < 8) {
    const int c = blockIdx.x * 256 + threadIdx.x;
    float m = -3.4e38f, s = 0.f;
    for (int seg = 0; seg < 32; ++seg)
      omax_merge(m, s, PM1[(size_t)seg * 2048 + c], PS1[(size_t)seg * 2048 + c], SC1);
    M1[c] = m;
    R1[c] = 1.0f / s;
  } else {
    const int c = (blockIdx.x - 8) * 256 + threadIdx.x;
    float m = -3.4e38f, s = 0.f;
    for (int seg = 0; seg < 8; ++seg)
      omax_merge(m, s, PM2[(size_t)seg * 2048 + c], PS2[(size_t)seg * 2048 + c], SC2);
    M2[c] = m;
    R2[c] = 1.0f / s;
  }
}

// ---------------- KNN v12: knn11 with float4-padded dx tail (1 ds_read_b128 per (q,k)) ----------------
__global__ __launch_bounds__(512, 8) void knn12_k(const float* __restrict__ xyz,
                                                  const float* __restrict__ fd1w, const float* __restrict__ fd1b,
                                                  ushort_t* __restrict__ HM, float* __restrict__ outxyz) {
  const int blk = blockIdx.x;            // 1024 blocks; 256 per batch; 16 queries/block
  const int b = blk >> 8;
  const int q0 = (blk & 255) * 16;
  const float* xb = xyz + (size_t)b * NN * 3;
  const int tid = threadIdx.x;
  const int lane = tid & 63, w = tid >> 6;

  __shared__ alignas(16) float px[2048], py[2048], pz[2048], pw2[2048];  // 32 KB
  __shared__ unsigned short candI[16][64];                               // 2 KB
  __shared__ int cnt[16];
  __shared__ alignas(16) float4 dx4[16][KNN];                            // 2.5 KB

  float qx[2], qy[2], qz[2], qn2[2];
  #pragma unroll
  for (int qq = 0; qq < 2; ++qq) {
    const int n = q0 + w * 2 + qq;
    qx[qq] = xb[n * 3]; qy[qq] = xb[n * 3 + 1]; qz[qq] = xb[n * 3 + 2];
    qn2[qq] = fmaf(qz[qq], qz[qq], fmaf(qy[qq], qy[qq], qx[qq] * qx[qq]));
  }
  if (tid < 16) cnt[tid] = 0;

  // pass 1: per-lane packed mins for 2 queries
  f32x2 mind[2];
  #pragma unroll
  for (int qq = 0; qq < 2; ++qq) mind[qq] = f32x2{3.4e38f, 3.4e38f};

  #pragma unroll
  for (int c = 0; c < 2; ++c) {
    __syncthreads();
    #pragma unroll
    for (int i = 0; i < 4; ++i) {
      const int p = i * 512 + tid;
      const int g = c * 2048 + p;
      const float x = xb[g * 3], y = xb[g * 3 + 1], z = xb[g * 3 + 2];
      px[p] = x; py[p] = y; pz[p] = z;
      pw2[p] = fmaf(z, z, fmaf(y, y, x * x));
    }
    __syncthreads();
    #pragma unroll 4
    for (int i = 0; i < 16; ++i) {
      const int p2 = i * 128 + lane * 2;
      const f32x2 x = *reinterpret_cast<const f32x2*>(&px[p2]);
      const f32x2 y = *reinterpret_cast<const f32x2*>(&py[p2]);
      const f32x2 z = *reinterpret_cast<const f32x2*>(&pz[p2]);
      const f32x2 pn = *reinterpret_cast<const f32x2*>(&pw2[p2]);
      #pragma unroll
      for (int qq = 0; qq < 2; ++qq) {
        f32x2 dot = x * qx[qq] + y * qy[qq] + z * qz[qq];
        const f32x2 dist = (pn + qn2[qq]) - (dot + dot);
        mind[qq].x = fminf(mind[qq].x, dist.x);
        mind[qq].y = fminf(mind[qq].y, dist.y);
      }
    }
  }

  // 2 bitonic float sorts; T[qq] = 10th smallest lane-min
  float T[2];
  #pragma unroll
  for (int qq = 0; qq < 2; ++qq) {
    float v = fminf(mind[qq].x, mind[qq].y);
    #pragma unroll
    for (int k = 2; k <= 64; k <<= 1) {
      #pragma unroll
      for (int j = k >> 1; j > 0; j >>= 1) {
        const float o = __shfl_xor(v, j);
        const bool keepMin = (((lane & k) == 0) == ((lane & j) == 0));
        v = keepMin ? fminf(v, o) : fmaxf(v, o);
      }
    }
    T[qq] = __shfl(v, 9);
  }

  // pass 2: chunk 1 resident -> scan first, then restage chunk 0
  #pragma unroll
  for (int cc = 0; cc < 2; ++cc) {
    const int c = 1 - cc;
    if (c == 0) {
      __syncthreads();
      #pragma unroll
      for (int i = 0; i < 4; ++i) {
        const int p = i * 512 + tid;
        const float x = xb[p * 3], y = xb[p * 3 + 1], z = xb[p * 3 + 2];
        px[p] = x; py[p] = y; pz[p] = z;
        pw2[p] = fmaf(z, z, fmaf(y, y, x * x));
      }
      __syncthreads();
    }
    const int gbase = c * 2048;
    #pragma unroll 2
    for (int i = 0; i < 16; ++i) {
      const int p2 = i * 128 + lane * 2;
      const f32x2 x = *reinterpret_cast<const f32x2*>(&px[p2]);
      const f32x2 y = *reinterpret_cast<const f32x2*>(&py[p2]);
      const f32x2 z = *reinterpret_cast<const f32x2*>(&pz[p2]);
      const f32x2 pn = *reinterpret_cast<const f32x2*>(&pw2[p2]);
      #pragma unroll
      for (int qq = 0; qq < 2; ++qq) {
        f32x2 dot = x * qx[qq] + y * qy[qq] + z * qz[qq];
        const f32x2 dist = (pn + qn2[qq]) - (dot + dot);
        const int q = w * 2 + qq;
        if (dist.x <= T[qq]) {
          const int slot = atomicAdd(&cnt[q], 1);
          if (slot < 64) candI[q][slot] = (unsigned short)(gbase + p2);
        }
        if (dist.y <= T[qq]) {
          const int slot = atomicAdd(&cnt[q], 1);
          if (slot < 64) candI[q][slot] = (unsigned short)(gbase + p2 + 1);
        }
      }
    }
  }

  // exact sort per query; lanes 0..9 produce neighbor deltas straight into LDS (float4-padded)
  #pragma unroll
  for (int qq = 0; qq < 2; ++qq) {
    const int q = w * 2 + qq;
    const int cN = cnt[q] < 64 ? cnt[q] : 64;
    ull cv = ~0ull;
    if (lane < cN) {
      const int p = candI[q][lane];
      const float x = xb[p * 3], y = xb[p * 3 + 1], z = xb[p * 3 + 2];
      const float pn2 = fmaf(z, z, fmaf(y, y, x * x));
      const float dot = fmaf(qz[qq], z, fmaf(qy[qq], y, qx[qq] * x));
      const float dist = fmaf(-2.f, dot, qn2[qq] + pn2);
      const unsigned u = __float_as_uint(dist);
      const unsigned key = u ^ (unsigned)(((int)u >> 31) | 0x80000000);
      cv = ((ull)key << 12) | (unsigned)p;
    }
    #pragma unroll
    for (int k = 2; k <= 64; k <<= 1) {
      #pragma unroll
      for (int j = k >> 1; j > 0; j >>= 1) {
        const ull o = __shfl_xor(cv, j);
        const bool keepMin = (((lane & k) == 0) == ((lane & j) == 0));
        const bool oLess = o < cv;
        cv = (keepMin == oLess) ? o : cv;
      }
    }
    if (lane < KNN) {
      const int p = (int)(cv & 0xFFFull);
      dx4[q][lane] = make_float4(qx[qq] - xb[p * 3],
                                 qy[qq] - xb[p * 3 + 1],
                                 qz[qq] - xb[p * 3 + 2], 0.f);
    }
  }

  // xyz passthrough for this block's 16 queries
  if (tid < 48) {
    const int q = tid / 3, c = tid - q * 3;
    outxyz[((size_t)(b * NN + q0 + q)) * 3 + c] = xb[(q0 + q) * 3 + c];
  }
  __syncthreads();

  // pos-enc hidden mean: thread = h, iterate 16 queries (one b128 broadcast per (q,k))
  const int h = tid;
  const float w0 = fd1w[h], w1 = fd1w[HH + h], w2 = fd1w[2 * HH + h], bbv = fd1b[h];
  #pragma unroll
  for (int q = 0; q < 16; ++q) {
    float acc = 0.f;
    #pragma unroll
    for (int k = 0; k < KNN; ++k) {
      const float4 d = dx4[q][k];
      acc += fmaxf(fmaf(d.z, w2, fmaf(d.y, w1, d.x * w0)) + bbv, 0.f);
    }
    HM[((size_t)(b * NN + q0 + q)) * HH + h] = bf1(acc * 0.1f);
  }
}

extern "C" void kernel_launch(void* const* d_in, const int* in_sizes, int n_in,
                              void* d_out, int out_size, void* d_ws, size_t ws_size,
                              hipStream_t stream) {
  const float* features = (const float*)d_in[0];
  const float* xyz      = (const float*)d_in[1];
  const float* fc1_w    = (const float*)d_in[2];
  const float* fc1_b    = (const float*)d_in[3];
  const float* fc2_w    = (const float*)d_in[4];
  const float* fc2_b    = (const float*)d_in[5];
  const float* fd1_w    = (const float*)d_in[6];
  const float* fd1_b    = (const float*)d_in[7];
  const float* fd2_w    = (const float*)d_in[8];
  const float* fd2_b    = (const float*)d_in[9];
  const float* fg1_w    = (const float*)d_in[10];
  const float* fg1_b    = (const float*)d_in[11];
  const float* fg2_w    = (const float*)d_in[12];
  const float* fg2_b    = (const float*)d_in[13];
  const float* fgh1_w   = (const float*)d_in[14];
  const float* fgh1_b   = (const float*)d_in[15];
  const float* fgh2_w   = (const float*)d_in[16];
  const float* fgh2_b   = (const float*)d_in[17];
  const float* wqs      = (const float*)d_in[18];
  const float* wks      = (const float*)d_in[19];
  const float* wvs      = (const float*)d_in[20];
  const float* wqs2     = (const float*)d_in[21];
  const float* wks2     = (const float*)d_in[22];
  float* out = (float*)d_out;

  const size_t BNH = (size_t)BB * NN * HH;       // 8388608
  // f32 region first
  float* PM1 = (float*)d_ws;
  float* PS1 = PM1 + 32 * 2048;
  float* PM2 = PS1 + 32 * 2048;
  float* PS2 = PM2 + 8 * 2048;
  float* M1  = PS2 + 8 * 2048;
  float* R1  = M1 + 2048;
  float* M2  = R1 + 2048;
  float* R2  = M2 + 2048;
  // bf16 region
  ushort_t* WT = (ushort_t*)(R2 + 2048);
  ushort_t* Xh = WT + WT_TOTAL;
  ushort_t* P  = Xh + BNH;
  ushort_t* HM = P + BNH;
  ushort_t* R  = HM + BNH;
  ushort_t* S1 = R + BNH;
  ushort_t* S2 = S1 + (size_t)BB * 1024 * HH;
  const size_t need = ((char*)(S2 + (size_t)BB * 1024 * HH)) - (char*)d_ws;
  if (ws_size < need) {
    fprintf(stderr, "kernel_launch: ws too small: %zu < %zu\n", ws_size, need);
    return;
  }

  // one-time weight convert/transpose to bf16 [n][k]
  wconv_k<<<(WT_TOTAL / 8 + 255) / 256, 256, 0, stream>>>(
      fc1_w, wqs2, wks2, fgh1_w, fgh2_w, wqs, wks, fg1_w, fg2_w, wvs, fd2_w, fc2_w, WT);

  // x = features^T @ fc1_w + fc1_b  -> Xh (bf16)
  mgemm_k<true, 1><<<dim3(HH / 128, NN / 128, BB), 256, 0, stream>>>(
      features, WT + OFF_FC1T, fc1_b, Xh, nullptr, NN, HH, CC, NN, (ll)CC * NN, (ll)NN * HH);

  // branch 1 fused chain -> P (bf16)
  fused1_k<<<512, 512, 0, stream>>>(Xh, WT + OFF_WD2T, WT + OFF_FGH1T, fgh1_b, WT + OFF_FGH2T, fgh2_b, P);

  // branch 2
  mgemm_k<false, 0><<<dim3(HH / 128, 1024 / 128, BB), 256, 0, stream>>>(
      Xh + (size_t)3072 * HH, WT + OFF_WDT, nullptr, S1, nullptr, 1024, HH, HH, HH, (ll)NN * HH, (ll)1024 * HH);
  mgemm_k<false, 2><<<dim3(HH / 128, BB * 1024 / 128, 1), 256, 0, stream>>>(
      S1, WT + OFF_FG1T, fg1_b, S2, nullptr, BB * 1024, HH, HH, HH, 0, 0);
  mgemm_k<false, 1><<<dim3(HH / 128, BB * 1024 / 128, 1), 256, 0, stream>>>(
      S2, WT + OFF_FG2T, fg2_b, S1, nullptr, BB * 1024, HH, HH, HH, 0, 0);

  // merged softmax reductions + combines
  red12_k<<<640, 256, 0, stream>>>(P, S1, PM1, PS1, PM2, PS2);
  combine12_k<<<16, 256, 0, stream>>>(PM1, PS1, PM2, PS2, M1, R1, M2, R2);

  // knn + fused pos-enc hidden mean + xyz passthrough
  knn12_k<<<BB * NN / 16, 512, 0, stream>>>(xyz, fd1_w, fd1_b, HM, out + (size_t)BB * CC * NN);

  // R = softmaxmix(P, S1) * (Xh@wvs + HM@fd2 + fd2_b)   (fused V + res, coalesced epilogue)
  gemm_vpe_res_k<<<dim3(HH / 128, BB * NN / 128, 1), 256, 0, stream>>>(
      Xh, HM, WT + OFF_WVST, WT + OFF_FD2T, fd2_b, P, S1, M1, R1, M2, R2, R);

  // out = swap(R @ fc2_w + fc2_b) + features (f32)
  mgemm_k<false, 4><<<dim3(CC / 128, NN / 128, BB), 256, 0, stream>>>(
      R, WT + OFF_FC2T, fc2_b, out, features, NN, CC, HH, HH, (ll)NN * HH, 0);
}

// Round 18
// 224.727 us; speedup vs baseline: 1.0316x; 1.0316x over previous
//
#include <hip/hip_runtime.h>
#include <cstdio>

typedef long long ll;
typedef unsigned long long ull;
typedef unsigned short ushort_t;
typedef __bf16 bf16x8 __attribute__((ext_vector_type(8)));
typedef float f32x4 __attribute__((ext_vector_type(4)));
typedef float f32x2 __attribute__((ext_vector_type(2)));

#define BB 4
#define NN 4096
#define CC 256
#define HH 512
#define GNUM 4
#define GS1 128
#define KNN 10

#define SC1 0.08838834764831845f   // 1/sqrt(128)
#define SC2 0.044194173824159216f  // 1/sqrt(512)

// WT segment offsets (elements)
#define OFF_FC1T   0
#define OFF_WD2T   131072
#define OFF_FGH1T  147456
#define OFF_FGH2T  163840
#define OFF_WDT    180224
#define OFF_FG1T   442368
#define OFF_FG2T   704512
#define OFF_WVST   966656
#define OFF_FD2T   1228800
#define OFF_FC2T   1490944
#define WT_TOTAL   1622016

__device__ inline unsigned pk2(float x, float y) {
  unsigned a = __float_as_uint(x), b = __float_as_uint(y);
  a = (a + 0x7FFFu + ((a >> 16) & 1u)) >> 16;
  b = (b + 0x7FFFu + ((b >> 16) & 1u)) >> 16;
  return a | (b << 16);
}
__device__ inline ushort_t bf1(float x) {
  unsigned a = __float_as_uint(x);
  return (ushort_t)((a + 0x7FFFu + ((a >> 16) & 1u)) >> 16);
}
__device__ inline float b2f(ushort_t u) { return __uint_as_float((unsigned)u << 16); }
__device__ inline int sw16(int r) { return ((r ^ (r >> 3)) & 7) << 4; }

// chunked bijective XCD swizzle (nwg must be divisible by 8)
__device__ inline void xcd_map(int& bx, int& by, int& bz) {
  const int nx = gridDim.x, ny = gridDim.y;
  const int nwg = nx * ny * gridDim.z;
  const int bidf = blockIdx.x + nx * (blockIdx.y + ny * blockIdx.z);
  const int lid = (bidf & 7) * (nwg >> 3) + (bidf >> 3);
  bx = lid % nx;
  const int rem = lid / nx;
  by = rem % ny;
  bz = rem / ny;
}

// ---------------- weight convert: WT[n][k] bf16 = (src - src2)[k][n] ----------------
__global__ __launch_bounds__(256) void wconv_k(
    const float* __restrict__ fc1w, const float* __restrict__ wqs2, const float* __restrict__ wks2,
    const float* __restrict__ fgh1, const float* __restrict__ fgh2,
    const float* __restrict__ wqs, const float* __restrict__ wks,
    const float* __restrict__ fg1, const float* __restrict__ fg2,
    const float* __restrict__ wvs, const float* __restrict__ fd2,
    const float* __restrict__ fc2w, ushort_t* __restrict__ WT)
{
  const int gc = blockIdx.x * 256 + threadIdx.x;
  const int e0 = gc * 8;
  if (e0 >= WT_TOTAL) return;
  const float* src = nullptr; const float* src2 = nullptr;
  int off, Kd, Nd;
  if (e0 < OFF_WD2T)        { src = fc1w;             off = OFF_FC1T;  Kd = 256; Nd = 512; }
  else if (e0 < OFF_FGH1T)  { src = wqs2; src2 = wks2; off = OFF_WD2T;  Kd = 128; Nd = 128; }
  else if (e0 < OFF_FGH2T)  { src = fgh1;             off = OFF_FGH1T; Kd = 128; Nd = 128; }
  else if (e0 < OFF_WDT)    { src = fgh2;             off = OFF_FGH2T; Kd = 128; Nd = 128; }
  else if (e0 < OFF_FG1T)   { src = wqs;  src2 = wks;  off = OFF_WDT;   Kd = 512; Nd = 512; }
  else if (e0 < OFF_FG2T)   { src = fg1;              off = OFF_FG1T;  Kd = 512; Nd = 512; }
  else if (e0 < OFF_WVST)   { src = fg2;              off = OFF_FG2T;  Kd = 512; Nd = 512; }
  else if (e0 < OFF_FD2T)   { src = wvs;              off = OFF_WVST;  Kd = 512; Nd = 512; }
  else if (e0 < OFF_FC2T)   { src = fd2;              off = OFF_FD2T;  Kd = 512; Nd = 512; }
  else                      { src = fc2w;             off = OFF_FC2T;  Kd = 512; Nd = 256; }
  const int local = e0 - off;
  const int n = local / Kd, k0 = local % Kd;
  ushort_t outv[8];
  #pragma unroll
  for (int j = 0; j < 8; ++j) {
    float v = src[(ll)(k0 + j) * Nd + n];
    if (src2) v -= src2[(ll)(k0 + j) * Nd + n];
    outv[j] = bf1(v);
  }
  *reinterpret_cast<uint4*>(WT + e0) = *reinterpret_cast<uint4*>(outv);
}

// ---------------- bf16 MFMA GEMM (B pre-transposed bf16 [n][k]) ----------------
// ATRANS: A f32 stored [k][m] with row stride lda. else A bf16 row-major [m][k].
// EPI: 0 store bf16, 1 +bias bf16, 2 +bias relu bf16, 4 +bias f32 transposed store + pre
template<bool ATRANS, int EPI>
__global__ __launch_bounds__(256, 2) void mgemm_k(
    const void* __restrict__ Ain, const ushort_t* __restrict__ BT,
    const float* __restrict__ bias, void* __restrict__ CoutV,
    const float* __restrict__ pre,
    int M, int N, int K, int lda, ll strideA, ll strideC)
{
  int bx, by, z;
  xcd_map(bx, by, z);
  const int bm = by * 128;
  const int bn = bx * 128;
  __shared__ alignas(16) char smem[32768];
  char* smA = smem;
  char* smB = smem + 16384;
  const int tid = threadIdx.x;
  const int lane = tid & 63, w = tid >> 6;
  const int lr = lane & 15, lg = lane >> 4;
  const int wm = (w & 1) * 64, wn = (w >> 1) * 64;

  const ushort_t* Ab = ATRANS ? nullptr : ((const ushort_t*)Ain + (ll)z * strideA);
  const float*    Af = ATRANS ? ((const float*)Ain + (ll)z * strideA) : nullptr;

  f32x4 acc[4][4] = {};

  for (int k0 = 0; k0 < K; k0 += 64) {
    if (!ATRANS) {
      #pragma unroll
      for (int p = 0; p < 4; ++p) {
        const int i = p * 256 + tid;
        const int r = i >> 3, c8 = (i & 7) * 8;
        const uint4 v = *reinterpret_cast<const uint4*>(Ab + (ll)(bm + r) * lda + (k0 + c8));
        *reinterpret_cast<uint4*>(smA + r * 128 + ((c8 * 2) ^ sw16(r))) = v;
      }
    } else {
      #pragma unroll
      for (int p = 0; p < 2; ++p) {
        const int bb = p * 256 + tid;
        const int mb = (bb & 31) * 4, kb = (bb >> 5) * 4;
        const float4 l0 = *reinterpret_cast<const float4*>(Af + (ll)(k0 + kb + 0) * lda + (bm + mb));
        const float4 l1 = *reinterpret_cast<const float4*>(Af + (ll)(k0 + kb + 1) * lda + (bm + mb));
        const float4 l2 = *reinterpret_cast<const float4*>(Af + (ll)(k0 + kb + 2) * lda + (bm + mb));
        const float4 l3 = *reinterpret_cast<const float4*>(Af + (ll)(k0 + kb + 3) * lda + (bm + mb));
        *reinterpret_cast<uint2*>(smA + (mb + 0) * 128 + ((kb * 2) ^ sw16(mb + 0))) = make_uint2(pk2(l0.x, l1.x), pk2(l2.x, l3.x));
        *reinterpret_cast<uint2*>(smA + (mb + 1) * 128 + ((kb * 2) ^ sw16(mb + 1))) = make_uint2(pk2(l0.y, l1.y), pk2(l2.y, l3.y));
        *reinterpret_cast<uint2*>(smA + (mb + 2) * 128 + ((kb * 2) ^ sw16(mb + 2))) = make_uint2(pk2(l0.z, l1.z), pk2(l2.z, l3.z));
        *reinterpret_cast<uint2*>(smA + (mb + 3) * 128 + ((kb * 2) ^ sw16(mb + 3))) = make_uint2(pk2(l0.w, l1.w), pk2(l2.w, l3.w));
      }
    }
    // B tile: rows n, cols k (pre-transposed bf16, row stride K)
    #pragma unroll
    for (int p = 0; p < 4; ++p) {
      const int i = p * 256 + tid;
      const int r = i >> 3, c8 = (i & 7) * 8;
      const uint4 v = *reinterpret_cast<const uint4*>(BT + (ll)(bn + r) * K + (k0 + c8));
      *reinterpret_cast<uint4*>(smB + r * 128 + ((c8 * 2) ^ sw16(r))) = v;
    }
    __syncthreads();

    #pragma unroll
    for (int ks = 0; ks < 2; ++ks) {
      bf16x8 af[4], bfr[4];
      #pragma unroll
      for (int mi = 0; mi < 4; ++mi) {
        const int r = wm + mi * 16 + lr;
        af[mi] = *reinterpret_cast<const bf16x8*>(smA + r * 128 + ((((ks << 2) + lg) << 4) ^ sw16(r)));
      }
      #pragma unroll
      for (int ni = 0; ni < 4; ++ni) {
        const int r = wn + ni * 16 + lr;
        bfr[ni] = *reinterpret_cast<const bf16x8*>(smB + r * 128 + ((((ks << 2) + lg) << 4) ^ sw16(r)));
      }
      #pragma unroll
      for (int mi = 0; mi < 4; ++mi)
        #pragma unroll
        for (int ni = 0; ni < 4; ++ni)
          acc[mi][ni] = __builtin_amdgcn_mfma_f32_16x16x32_bf16(af[mi], bfr[ni], acc[mi][ni], 0, 0, 0);
    }
    __syncthreads();
  }

  #pragma unroll
  for (int ni = 0; ni < 4; ++ni) {
    const int col = bn + wn + ni * 16 + lr;
    const float bv = (EPI != 0) ? bias[col] : 0.f;
    #pragma unroll
    for (int mi = 0; mi < 4; ++mi) {
      const int row0 = bm + wm + mi * 16 + lg * 4;
      if (EPI == 4) {
        float* Cout = (float*)CoutV;
        const size_t o = ((size_t)z * N + col) * (size_t)M + row0;
        const float4 pv = *reinterpret_cast<const float4*>(pre + o);
        float4 r;
        r.x = acc[mi][ni][0] + bv + pv.x;
        r.y = acc[mi][ni][1] + bv + pv.y;
        r.z = acc[mi][ni][2] + bv + pv.z;
        r.w = acc[mi][ni][3] + bv + pv.w;
        *reinterpret_cast<float4*>(Cout + o) = r;
      } else {
        ushort_t* Co = (ushort_t*)CoutV + (ll)z * strideC;
        #pragma unroll
        for (int i = 0; i < 4; ++i) {
          float val = acc[mi][ni][i] + bv;
          if (EPI == 2) val = fmaxf(val, 0.f);
          Co[(ll)(row0 + i) * N + col] = bf1(val);
        }
      }
    }
  }
}

// ---------------- fused V+res kernel: R = softmaxmix(P,A2) * (X@wvT + HM@fd2T + bias) ----------------
// Epilogue stages V into a padded LDS tile, then does a fully coalesced res pass.
__global__ __launch_bounds__(256, 2) void gemm_vpe_res_k(
    const ushort_t* __restrict__ X, const ushort_t* __restrict__ HM,
    const ushort_t* __restrict__ wvT, const ushort_t* __restrict__ w2T,
    const float* __restrict__ bias,
    const ushort_t* __restrict__ P, const ushort_t* __restrict__ A2,
    const float* __restrict__ M1, const float* __restrict__ R1,
    const float* __restrict__ M2, const float* __restrict__ R2,
    ushort_t* __restrict__ Rout)
{
  int bx, by, z;
  xcd_map(bx, by, z);
  const int bm = by * 128;
  const int bn = bx * 128;
  __shared__ alignas(16) char smem[34816];   // K-loop: smA(16K)+smB(16K); epilogue: Vt[128][136] bf16
  char* smA = smem;
  char* smB = smem + 16384;
  const int tid = threadIdx.x;
  const int lane = tid & 63, w = tid >> 6;
  const int lr = lane & 15, lg = lane >> 4;
  const int wm = (w & 1) * 64, wn = (w >> 1) * 64;

  f32x4 acc[4][4] = {};

  for (int k0 = 0; k0 < 1024; k0 += 64) {
    const ushort_t* A = (k0 < 512) ? X : HM;
    const ushort_t* BT = (k0 < 512) ? wvT : w2T;
    const int kk = k0 & 511;
    #pragma unroll
    for (int p = 0; p < 4; ++p) {
      const int i = p * 256 + tid;
      const int r = i >> 3, c8 = (i & 7) * 8;
      const uint4 v = *reinterpret_cast<const uint4*>(A + (ll)(bm + r) * 512 + (kk + c8));
      *reinterpret_cast<uint4*>(smA + r * 128 + ((c8 * 2) ^ sw16(r))) = v;
    }
    #pragma unroll
    for (int p = 0; p < 4; ++p) {
      const int i = p * 256 + tid;
      const int r = i >> 3, c8 = (i & 7) * 8;
      const uint4 v = *reinterpret_cast<const uint4*>(BT + (ll)(bn + r) * 512 + (kk + c8));
      *reinterpret_cast<uint4*>(smB + r * 128 + ((c8 * 2) ^ sw16(r))) = v;
    }
    __syncthreads();

    #pragma unroll
    for (int ks = 0; ks < 2; ++ks) {
      bf16x8 af[4], bfr[4];
      #pragma unroll
      for (int mi = 0; mi < 4; ++mi) {
        const int r = wm + mi * 16 + lr;
        af[mi] = *reinterpret_cast<const bf16x8*>(smA + r * 128 + ((((ks << 2) + lg) << 4) ^ sw16(r)));
      }
      #pragma unroll
      for (int ni = 0; ni < 4; ++ni) {
        const int r = wn + ni * 16 + lr;
        bfr[ni] = *reinterpret_cast<const bf16x8*>(smB + r * 128 + ((((ks << 2) + lg) << 4) ^ sw16(r)));
      }
      #pragma unroll
      for (int mi = 0; mi < 4; ++mi)
        #pragma unroll
        for (int ni = 0; ni < 4; ++ni)
          acc[mi][ni] = __builtin_amdgcn_mfma_f32_16x16x32_bf16(af[mi], bfr[ni], acc[mi][ni], 0, 0, 0);
    }
    __syncthreads();
  }

  // stage V (+bias) into padded LDS tile (last __syncthreads already passed)
  ushort_t (*Vt)[136] = reinterpret_cast<ushort_t (*)[136]>(smem);
  #pragma unroll
  for (int ni = 0; ni < 4; ++ni) {
    const int col = wn + ni * 16 + lr;
    const float bv = bias[bn + col];
    #pragma unroll
    for (int mi = 0; mi < 4; ++mi) {
      const int row0 = wm + mi * 16 + lg * 4;
      #pragma unroll
      for (int i = 0; i < 4; ++i)
        Vt[row0 + i][col] = bf1(acc[mi][ni][i] + bv);
    }
  }
  __syncthreads();

  // coalesced res pass: 8 contiguous cols per thread-chunk
  const int bb = bm >> 12;          // batch index (block rows never straddle a batch)
  for (int it = 0; it < 8; ++it) {
    const int chunk = it * 256 + tid;
    const int lrow = chunk >> 4;
    const int c8 = (chunk & 15) * 8;
    const int grow = bm + lrow;
    const int gcol = bn + c8;
    const int rb = grow & 1023;
    const uint4 pu = *reinterpret_cast<const uint4*>(P + (ll)grow * 512 + gcol);
    const uint4 au = *reinterpret_cast<const uint4*>(A2 + ((ll)bb * 1024 + rb) * 512 + gcol);
    const uint4 vu = *reinterpret_cast<const uint4*>(&Vt[lrow][c8]);
    const int c = bb * 512 + gcol;
    float m1v[8], r1v[8], m2v[8], r2v[8];
    *reinterpret_cast<float4*>(m1v)     = *reinterpret_cast<const float4*>(M1 + c);
    *reinterpret_cast<float4*>(m1v + 4) = *reinterpret_cast<const float4*>(M1 + c + 4);
    *reinterpret_cast<float4*>(r1v)     = *reinterpret_cast<const float4*>(R1 + c);
    *reinterpret_cast<float4*>(r1v + 4) = *reinterpret_cast<const float4*>(R1 + c + 4);
    *reinterpret_cast<float4*>(m2v)     = *reinterpret_cast<const float4*>(M2 + c);
    *reinterpret_cast<float4*>(m2v + 4) = *reinterpret_cast<const float4*>(M2 + c + 4);
    *reinterpret_cast<float4*>(r2v)     = *reinterpret_cast<const float4*>(R2 + c);
    *reinterpret_cast<float4*>(r2v + 4) = *reinterpret_cast<const float4*>(R2 + c + 4);
    const unsigned* pw = reinterpret_cast<const unsigned*>(&pu);
    const unsigned* aw = reinterpret_cast<const unsigned*>(&au);
    const unsigned* vw = reinterpret_cast<const unsigned*>(&vu);
    float r[8];
    #pragma unroll
    for (int e = 0; e < 8; ++e) {
      const unsigned wsel = (e >> 1);
      const ushort_t pv = (ushort_t)((pw[wsel] >> ((e & 1) * 16)) & 0xFFFF);
      const ushort_t av = (ushort_t)((aw[wsel] >> ((e & 1) * 16)) & 0xFFFF);
      const ushort_t vv = (ushort_t)((vw[wsel] >> ((e & 1) * 16)) & 0xFFFF);
      r[e] = (expf((b2f(pv) - m1v[e]) * SC1) * r1v[e] + expf((b2f(av) - m2v[e]) * SC2) * r2v[e]) * b2f(vv);
    }
    uint4 ru;
    ru.x = pk2(r[0], r[1]);
    ru.y = pk2(r[2], r[3]);
    ru.z = pk2(r[4], r[5]);
    ru.w = pk2(r[6], r[7]);
    *reinterpret_cast<uint4*>(Rout + (ll)grow * 512 + gcol) = ru;
  }
}

// ---------------- fused branch-1 chain ----------------
__device__ __forceinline__ void gemm128(const char* smA, const char* smW, int wrow, int lr, int lg,
                                        f32x4 acc[8]) {
  #pragma unroll
  for (int ks = 0; ks < 4; ++ks) {
    const int koff = (ks * 4 + lg) * 16;
    const int ra = wrow + lr;
    const bf16x8 a = *reinterpret_cast<const bf16x8*>(smA + ra * 256 + (koff ^ sw16(ra)));
    #pragma unroll
    for (int ni = 0; ni < 8; ++ni) {
      const int rn = ni * 16 + lr;
      const bf16x8 b = *reinterpret_cast<const bf16x8*>(smW + rn * 256 + (koff ^ sw16(rn)));
      acc[ni] = __builtin_amdgcn_mfma_f32_16x16x32_bf16(a, b, acc[ni], 0, 0, 0);
    }
  }
}

// stage 128x128 bf16 weight (pre-transposed [n][k]) into swizzled LDS
__device__ __forceinline__ void stageWTb(const ushort_t* __restrict__ W, char* smW, int tid) {
  #pragma unroll
  for (int p = 0; p < 4; ++p) {
    const int i = p * 512 + tid;
    const int r = i >> 4, c8 = (i & 15) * 8;
    const uint4 v = *reinterpret_cast<const uint4*>(W + r * 128 + c8);
    *reinterpret_cast<uint4*>(smW + r * 256 + ((c8 * 2) ^ sw16(r))) = v;
  }
}

__global__ __launch_bounds__(512, 4) void fused1_k(
    const ushort_t* __restrict__ X,
    const ushort_t* __restrict__ wd2T,
    const ushort_t* __restrict__ w2T, const float* __restrict__ b2g,
    const ushort_t* __restrict__ w3T, const float* __restrict__ b3g,
    ushort_t* __restrict__ P)
{
  __shared__ alignas(16) char smT[32768];
  __shared__ alignas(16) char smW[32768];
  const int tid = threadIdx.x;
  const int lane = tid & 63, w = tid >> 6;
  const int lr = lane & 15, lg = lane >> 4;
  const int wrow = w * 16;
  const ll blockRow = (ll)blockIdx.x * 128;
  const ushort_t* Xb = X + blockRow * 128;

  float b2r[8], b3r[8];
  #pragma unroll
  for (int ni = 0; ni < 8; ++ni) { b2r[ni] = b2g[ni * 16 + lr]; b3r[ni] = b3g[ni * 16 + lr]; }

  #pragma unroll
  for (int p = 0; p < 4; ++p) {
    const int i = p * 512 + tid;
    const int r = i >> 4, c8 = (i & 15) * 8;
    const uint4 v = *reinterpret_cast<const uint4*>(Xb + (ll)r * 128 + c8);
    *reinterpret_cast<uint4*>(smT + r * 256 + ((c8 * 2) ^ sw16(r))) = v;
  }
  stageWTb(wd2T, smW, tid);
  __syncthreads();

  f32x4 acc[8];
  #pragma unroll
  for (int ni = 0; ni < 8; ++ni) acc[ni] = f32x4{0.f, 0.f, 0.f, 0.f};
  gemm128(smT, smW, wrow, lr, lg, acc);        // T1 = X @ WD2
  __syncthreads();

  #pragma unroll
  for (int ni = 0; ni < 8; ++ni)
    #pragma unroll
    for (int i = 0; i < 4; ++i) {
      const int r = wrow + lg * 4 + i;
      *reinterpret_cast<ushort_t*>(smT + r * 256 + (((ni * 16 + lr) * 2) ^ sw16(r))) = bf1(acc[ni][i]);
    }
  stageWTb(w2T, smW, tid);
  __syncthreads();

  #pragma unroll
  for (int ni = 0; ni < 8; ++ni) acc[ni] = f32x4{0.f, 0.f, 0.f, 0.f};
  gemm128(smT, smW, wrow, lr, lg, acc);        // U = T1 @ fgh1
  __syncthreads();

  #pragma unroll
  for (int ni = 0; ni < 8; ++ni)
    #pragma unroll
    for (int i = 0; i < 4; ++i) {
      const int r = wrow + lg * 4 + i;
      *reinterpret_cast<ushort_t*>(smT + r * 256 + (((ni * 16 + lr) * 2) ^ sw16(r))) =
          bf1(fmaxf(acc[ni][i] + b2r[ni], 0.f));
    }
  stageWTb(w3T, smW, tid);
  __syncthreads();

  #pragma unroll
  for (int ni = 0; ni < 8; ++ni) acc[ni] = f32x4{0.f, 0.f, 0.f, 0.f};
  gemm128(smT, smW, wrow, lr, lg, acc);        // P = U @ fgh2

  #pragma unroll
  for (int ni = 0; ni < 8; ++ni)
    #pragma unroll
    for (int i = 0; i < 4; ++i) {
      const ll r = blockRow + wrow + lg * 4 + i;
      P[r * 128 + ni * 16 + lr] = bf1(acc[ni][i] + b3r[ni]);
    }
}

// ---------------- online softmax partial reduce (bf16 inputs), merged ----------------
__device__ inline void omax_upd(float& m, float& s, float v, float scale) {
  if (v > m) { s = s * expf((m - v) * scale) + 1.0f; m = v; }
  else       { s += expf((v - m) * scale); }
}
__device__ inline void omax_merge(float& m, float& s, float m2, float s2, float scale) {
  if (m2 > m) { s = s * expf((m - m2) * scale) + s2; m = m2; }
  else        { s += s2 * expf((m2 - m) * scale); }
}

// grid 640: blocks [0,512) = branch-1 reduce, [512,640) = branch-2 reduce
__global__ __launch_bounds__(256) void red12_k(const ushort_t* __restrict__ P, const ushort_t* __restrict__ A2,
                                               float* __restrict__ PM1, float* __restrict__ PS1,
                                               float* __restrict__ PM2, float* __restrict__ PS2) {
  __shared__ float sm[256], ss[256];
  if (blockIdx.x < 512) {
    const int bid = blockIdx.x;
    const int b = bid >> 7, g = (bid >> 5) & 3, seg = bid & 31;
    const int d = threadIdx.x & 127, half = threadIdx.x >> 7;
    const size_t base = (size_t)b * NN * HH + g * GS1 + d;
    float m = -3.4e38f, s = 0.f;
    const int n0 = seg * 128 + half * 64;
    for (int n = n0; n < n0 + 64; ++n)
      omax_upd(m, s, b2f(P[base + (size_t)n * HH]), SC1);
    sm[threadIdx.x] = m; ss[threadIdx.x] = s;
    __syncthreads();
    if (half == 0) {
      omax_merge(m, s, sm[threadIdx.x + 128], ss[threadIdx.x + 128], SC1);
      const int c = b * HH + g * GS1 + d;
      PM1[(size_t)seg * 2048 + c] = m;
      PS1[(size_t)seg * 2048 + c] = s;
    }
  } else {
    const int bid = blockIdx.x - 512;
    const int b = bid >> 5, hb = (bid >> 3) & 3, seg = bid & 7;
    const int hl = threadIdx.x & 127, half = threadIdx.x >> 7;
    const int h = hb * 128 + hl;
    const size_t base = (size_t)b * 1024 * HH + h;
    float m = -3.4e38f, s = 0.f;
    const int r0 = seg * 128 + half * 64;
    for (int r = r0; r < r0 + 64; ++r)
      omax_upd(m, s, b2f(A2[base + (size_t)r * HH]), SC2);
    sm[threadIdx.x] = m; ss[threadIdx.x] = s;
    __syncthreads();
    if (half == 0) {
      omax_merge(m, s, sm[threadIdx.x + 128], ss[threadIdx.x + 128], SC2);
      const int c = b * HH + h;
      PM2[(size_t)seg * 2048 + c] = m;
      PS2[(size_t)seg * 2048 + c] = s;
    }
  }
}

// grid 16: blocks [0,8) combine branch-1 (nseg 32, SC1), [8,16) combine branch-2 (nseg 8, SC2)
__global__ __launch_bounds__(256) void combine12_k(const float* __restrict__ PM1, const float* __restrict__ PS1,
                                                   const float* __restrict__ PM2, const float* __restrict__ PS2,
                                                   float* __restrict__ M1, float* __restrict__ R1,
                                                   float* __restrict__ M2, float* __restrict__ R2) {
  if (blockIdx.x < 8) {
    const int c = blockIdx.x * 256 + threadIdx.x;
    float m = -3.4e38f, s = 0.f;
    for (int seg = 0; seg < 32; ++seg)
      omax_merge(m, s, PM1[(size_t)seg * 2048 + c], PS1[(size_t)seg * 2048 + c], SC1);
    M1[c] = m;
    R1[c] = 1.0f / s;
  } else {
    const int c = (blockIdx.x - 8) * 256 + threadIdx.x;
    float m = -3.4e38f, s = 0.f;
    for (int seg = 0; seg < 8; ++seg)
      omax_merge(m, s, PM2[(size_t)seg * 2048 + c], PS2[(size_t)seg * 2048 + c], SC2);
    M2[c] = m;
    R2[c] = 1.0f / s;
  }
}

// ---------------- KNN v11: knn10 + fused pos-enc hidden mean + xyz passthrough ----------------
__global__ __launch_bounds__(512, 8) void knn11_k(const float* __restrict__ xyz,
                                                  const float* __restrict__ fd1w, const float* __restrict__ fd1b,
                                                  ushort_t* __restrict__ HM, float* __restrict__ outxyz) {
  const int blk = blockIdx.x;            // 1024 blocks; 256 per batch; 16 queries/block
  const int b = blk >> 8;
  const int q0 = (blk & 255) * 16;
  const float* xb = xyz + (size_t)b * NN * 3;
  const int tid = threadIdx.x;
  const int lane = tid & 63, w = tid >> 6;

  __shared__ alignas(16) float px[2048], py[2048], pz[2048], pw2[2048];  // 32 KB
  __shared__ unsigned short candI[16][64];                               // 2 KB
  __shared__ int cnt[16];
  __shared__ float dx[16][KNN][3];                                       // 1.9 KB

  float qx[2], qy[2], qz[2], qn2[2];
  #pragma unroll
  for (int qq = 0; qq < 2; ++qq) {
    const int n = q0 + w * 2 + qq;
    qx[qq] = xb[n * 3]; qy[qq] = xb[n * 3 + 1]; qz[qq] = xb[n * 3 + 2];
    qn2[qq] = fmaf(qz[qq], qz[qq], fmaf(qy[qq], qy[qq], qx[qq] * qx[qq]));
  }
  if (tid < 16) cnt[tid] = 0;

  // pass 1: per-lane packed mins for 2 queries
  f32x2 mind[2];
  #pragma unroll
  for (int qq = 0; qq < 2; ++qq) mind[qq] = f32x2{3.4e38f, 3.4e38f};

  #pragma unroll
  for (int c = 0; c < 2; ++c) {
    __syncthreads();
    #pragma unroll
    for (int i = 0; i < 4; ++i) {
      const int p = i * 512 + tid;
      const int g = c * 2048 + p;
      const float x = xb[g * 3], y = xb[g * 3 + 1], z = xb[g * 3 + 2];
      px[p] = x; py[p] = y; pz[p] = z;
      pw2[p] = fmaf(z, z, fmaf(y, y, x * x));
    }
    __syncthreads();
    #pragma unroll 4
    for (int i = 0; i < 16; ++i) {
      const int p2 = i * 128 + lane * 2;
      const f32x2 x = *reinterpret_cast<const f32x2*>(&px[p2]);
      const f32x2 y = *reinterpret_cast<const f32x2*>(&py[p2]);
      const f32x2 z = *reinterpret_cast<const f32x2*>(&pz[p2]);
      const f32x2 pn = *reinterpret_cast<const f32x2*>(&pw2[p2]);
      #pragma unroll
      for (int qq = 0; qq < 2; ++qq) {
        f32x2 dot = x * qx[qq] + y * qy[qq] + z * qz[qq];
        const f32x2 dist = (pn + qn2[qq]) - (dot + dot);
        mind[qq].x = fminf(mind[qq].x, dist.x);
        mind[qq].y = fminf(mind[qq].y, dist.y);
      }
    }
  }

  // 2 bitonic float sorts; T[qq] = 10th smallest lane-min
  float T[2];
  #pragma unroll
  for (int qq = 0; qq < 2; ++qq) {
    float v = fminf(mind[qq].x, mind[qq].y);
    #pragma unroll
    for (int k = 2; k <= 64; k <<= 1) {
      #pragma unroll
      for (int j = k >> 1; j > 0; j >>= 1) {
        const float o = __shfl_xor(v, j);
        const bool keepMin = (((lane & k) == 0) == ((lane & j) == 0));
        v = keepMin ? fminf(v, o) : fmaxf(v, o);
      }
    }
    T[qq] = __shfl(v, 9);
  }

  // pass 2: chunk 1 resident -> scan first, then restage chunk 0
  #pragma unroll
  for (int cc = 0; cc < 2; ++cc) {
    const int c = 1 - cc;
    if (c == 0) {
      __syncthreads();
      #pragma unroll
      for (int i = 0; i < 4; ++i) {
        const int p = i * 512 + tid;
        const float x = xb[p * 3], y = xb[p * 3 + 1], z = xb[p * 3 + 2];
        px[p] = x; py[p] = y; pz[p] = z;
        pw2[p] = fmaf(z, z, fmaf(y, y, x * x));
      }
      __syncthreads();
    }
    const int gbase = c * 2048;
    #pragma unroll 2
    for (int i = 0; i < 16; ++i) {
      const int p2 = i * 128 + lane * 2;
      const f32x2 x = *reinterpret_cast<const f32x2*>(&px[p2]);
      const f32x2 y = *reinterpret_cast<const f32x2*>(&py[p2]);
      const f32x2 z = *reinterpret_cast<const f32x2*>(&pz[p2]);
      const f32x2 pn = *reinterpret_cast<const f32x2*>(&pw2[p2]);
      #pragma unroll
      for (int qq = 0; qq < 2; ++qq) {
        f32x2 dot = x * qx[qq] + y * qy[qq] + z * qz[qq];
        const f32x2 dist = (pn + qn2[qq]) - (dot + dot);
        const int q = w * 2 + qq;
        if (dist.x <= T[qq]) {
          const int slot = atomicAdd(&cnt[q], 1);
          if (slot < 64) candI[q][slot] = (unsigned short)(gbase + p2);
        }
        if (dist.y <= T[qq]) {
          const int slot = atomicAdd(&cnt[q], 1);
          if (slot < 64) candI[q][slot] = (unsigned short)(gbase + p2 + 1);
        }
      }
    }
  }

  // exact sort per query; lanes 0..9 produce neighbor deltas straight into LDS
  #pragma unroll
  for (int qq = 0; qq < 2; ++qq) {
    const int q = w * 2 + qq;
    const int cN = cnt[q] < 64 ? cnt[q] : 64;
    ull cv = ~0ull;
    if (lane < cN) {
      const int p = candI[q][lane];
      const float x = xb[p * 3], y = xb[p * 3 + 1], z = xb[p * 3 + 2];
      const float pn2 = fmaf(z, z, fmaf(y, y, x * x));
      const float dot = fmaf(qz[qq], z, fmaf(qy[qq], y, qx[qq] * x));
      const float dist = fmaf(-2.f, dot, qn2[qq] + pn2);
      const unsigned u = __float_as_uint(dist);
      const unsigned key = u ^ (unsigned)(((int)u >> 31) | 0x80000000);
      cv = ((ull)key << 12) | (unsigned)p;
    }
    #pragma unroll
    for (int k = 2; k <= 64; k <<= 1) {
      #pragma unroll
      for (int j = k >> 1; j > 0; j >>= 1) {
        const ull o = __shfl_xor(cv, j);
        const bool keepMin = (((lane & k) == 0) == ((lane & j) == 0));
        const bool oLess = o < cv;
        cv = (keepMin == oLess) ? o : cv;
      }
    }
    if (lane < KNN) {
      const int p = (int)(cv & 0xFFFull);
      dx[q][lane][0] = qx[qq] - xb[p * 3];
      dx[q][lane][1] = qy[qq] - xb[p * 3 + 1];
      dx[q][lane][2] = qz[qq] - xb[p * 3 + 2];
    }
  }

  // xyz passthrough for this block's 16 queries
  if (tid < 48) {
    const int q = tid / 3, c = tid - q * 3;
    outxyz[((size_t)(b * NN + q0 + q)) * 3 + c] = xb[(q0 + q) * 3 + c];
  }
  __syncthreads();

  // pos-enc hidden mean: thread = h, iterate 16 queries (dx reads are LDS broadcasts)
  const int h = tid;
  const float w0 = fd1w[h], w1 = fd1w[HH + h], w2 = fd1w[2 * HH + h], bbv = fd1b[h];
  #pragma unroll
  for (int q = 0; q < 16; ++q) {
    float acc = 0.f;
    #pragma unroll
    for (int k = 0; k < KNN; ++k)
      acc += fmaxf(fmaf(dx[q][k][2], w2, fmaf(dx[q][k][1], w1, dx[q][k][0] * w0)) + bbv, 0.f);
    HM[((size_t)(b * NN + q0 + q)) * HH + h] = bf1(acc * 0.1f);
  }
}

extern "C" void kernel_launch(void* const* d_in, const int* in_sizes, int n_in,
                              void* d_out, int out_size, void* d_ws, size_t ws_size,
                              hipStream_t stream) {
  const float* features = (const float*)d_in[0];
  const float* xyz      = (const float*)d_in[1];
  const float* fc1_w    = (const float*)d_in[2];
  const float* fc1_b    = (const float*)d_in[3];
  const float* fc2_w    = (const float*)d_in[4];
  const float* fc2_b    = (const float*)d_in[5];
  const float* fd1_w    = (const float*)d_in[6];
  const float* fd1_b    = (const float*)d_in[7];
  const float* fd2_w    = (const float*)d_in[8];
  const float* fd2_b    = (const float*)d_in[9];
  const float* fg1_w    = (const float*)d_in[10];
  const float* fg1_b    = (const float*)d_in[11];
  const float* fg2_w    = (const float*)d_in[12];
  const float* fg2_b    = (const float*)d_in[13];
  const float* fgh1_w   = (const float*)d_in[14];
  const float* fgh1_b   = (const float*)d_in[15];
  const float* fgh2_w   = (const float*)d_in[16];
  const float* fgh2_b   = (const float*)d_in[17];
  const float* wqs      = (const float*)d_in[18];
  const float* wks      = (const float*)d_in[19];
  const float* wvs      = (const float*)d_in[20];
  const float* wqs2     = (const float*)d_in[21];
  const float* wks2     = (const float*)d_in[22];
  float* out = (float*)d_out;

  const size_t BNH = (size_t)BB * NN * HH;       // 8388608
  // f32 region first
  float* PM1 = (float*)d_ws;
  float* PS1 = PM1 + 32 * 2048;
  float* PM2 = PS1 + 32 * 2048;
  float* PS2 = PM2 + 8 * 2048;
  float* M1  = PS2 + 8 * 2048;
  float* R1  = M1 + 2048;
  float* M2  = R1 + 2048;
  float* R2  = M2 + 2048;
  // bf16 region
  ushort_t* WT = (ushort_t*)(R2 + 2048);
  ushort_t* Xh = WT + WT_TOTAL;
  ushort_t* P  = Xh + BNH;
  ushort_t* HM = P + BNH;
  ushort_t* R  = HM + BNH;
  ushort_t* S1 = R + BNH;
  ushort_t* S2 = S1 + (size_t)BB * 1024 * HH;
  const size_t need = ((char*)(S2 + (size_t)BB * 1024 * HH)) - (char*)d_ws;
  if (ws_size < need) {
    fprintf(stderr, "kernel_launch: ws too small: %zu < %zu\n", ws_size, need);
    return;
  }

  // one-time weight convert/transpose to bf16 [n][k]
  wconv_k<<<(WT_TOTAL / 8 + 255) / 256, 256, 0, stream>>>(
      fc1_w, wqs2, wks2, fgh1_w, fgh2_w, wqs, wks, fg1_w, fg2_w, wvs, fd2_w, fc2_w, WT);

  // x = features^T @ fc1_w + fc1_b  -> Xh (bf16)
  mgemm_k<true, 1><<<dim3(HH / 128, NN / 128, BB), 256, 0, stream>>>(
      features, WT + OFF_FC1T, fc1_b, Xh, nullptr, NN, HH, CC, NN, (ll)CC * NN, (ll)NN * HH);

  // branch 1 fused chain -> P (bf16)
  fused1_k<<<512, 512, 0, stream>>>(Xh, WT + OFF_WD2T, WT + OFF_FGH1T, fgh1_b, WT + OFF_FGH2T, fgh2_b, P);

  // branch 2
  mgemm_k<false, 0><<<dim3(HH / 128, 1024 / 128, BB), 256, 0, stream>>>(
      Xh + (size_t)3072 * HH, WT + OFF_WDT, nullptr, S1, nullptr, 1024, HH, HH, HH, (ll)NN * HH, (ll)1024 * HH);
  mgemm_k<false, 2><<<dim3(HH / 128, BB * 1024 / 128, 1), 256, 0, stream>>>(
      S1, WT + OFF_FG1T, fg1_b, S2, nullptr, BB * 1024, HH, HH, HH, 0, 0);
  mgemm_k<false, 1><<<dim3(HH / 128, BB * 1024 / 128, 1), 256, 0, stream>>>(
      S2, WT + OFF_FG2T, fg2_b, S1, nullptr, BB * 1024, HH, HH, HH, 0, 0);

  // merged softmax reductions + combines
  red12_k<<<640, 256, 0, stream>>>(P, S1, PM1, PS1, PM2, PS2);
  combine12_k<<<16, 256, 0, stream>>>(PM1, PS1, PM2, PS2, M1, R1, M2, R2);

  // knn + fused pos-enc hidden mean + xyz passthrough
  knn11_k<<<BB * NN / 16, 512, 0, stream>>>(xyz, fd1_w, fd1_b, HM, out + (size_t)BB * CC * NN);

  // R = softmaxmix(P, S1) * (Xh@wvs + HM@fd2 + fd2_b)   (fused V + res, coalesced epilogue)
  gemm_vpe_res_k<<<dim3(HH / 128, BB * NN / 128, 1), 256, 0, stream>>>(
      Xh, HM, WT + OFF_WVST, WT + OFF_FD2T, fd2_b, P, S1, M1, R1, M2, R2, R);

  // out = swap(R @ fc2_w + fc2_b) + features (f32)
  mgemm_k<false, 4><<<dim3(CC / 128, NN / 128, BB), 256, 0, stream>>>(
      R, WT + OFF_FC2T, fc2_b, out, features, NN, CC, HH, HH, (ll)NN * HH, 0);
}